// Round 2
// baseline (328.879 us; speedup 1.0000x reference)
//
#include <hip/hip_runtime.h>
#include <hip/hip_bf16.h>

typedef _Float16 half8 __attribute__((ext_vector_type(8)));
typedef float floatx4 __attribute__((ext_vector_type(4)));

#define LOG2E 1.44269504088896340736f

__device__ __forceinline__ half8 cvt8(const float* p) {
    floatx4 a = *(const floatx4*)p;
    floatx4 b = *(const floatx4*)(p + 4);
    half8 h;
    h[0] = (_Float16)a[0]; h[1] = (_Float16)a[1]; h[2] = (_Float16)a[2]; h[3] = (_Float16)a[3];
    h[4] = (_Float16)b[0]; h[5] = (_Float16)b[1]; h[6] = (_Float16)b[2]; h[7] = (_Float16)b[3];
    return h;
}

// ---------------- K1: transpose + convert W (f32 [512x512]) -> WT fp16 [n][k] ----------------
__global__ __launch_bounds__(256) void transpose_w_kernel(
        const float* __restrict__ Wq, const float* __restrict__ Wk,
        const float* __restrict__ Wv, const float* __restrict__ Wo,
        _Float16* __restrict__ out) {
    const float* W = (blockIdx.z == 0) ? Wq : (blockIdx.z == 1) ? Wk : (blockIdx.z == 2) ? Wv : Wo;
    _Float16* o = out + (size_t)blockIdx.z * 512 * 512;
    __shared__ __align__(16) _Float16 t[64][72];
    int r0 = blockIdx.x * 64, c0 = blockIdx.y * 64;
    int tid = threadIdx.x;
    for (int i = 0; i < 2; i++) {
        int f = i * 256 + tid;
        int row = f >> 3, seg = f & 7;
        *(half8*)&t[row][seg * 8] = cvt8(W + (size_t)(r0 + row) * 512 + c0 + seg * 8);
    }
    __syncthreads();
    for (int i = 0; i < 2; i++) {
        int f = i * 256 + tid;
        int crow = f >> 3, seg = f & 7;
        half8 hv;
        for (int j = 0; j < 8; j++) hv[j] = t[seg * 8 + j][crow];
        *(half8*)(o + (size_t)(c0 + crow) * 512 + r0 + seg * 8) = hv;
    }
}

// ---------------- K2: QKV projection GEMM: C = X(f32->fp16) @ W + b -> fp16 [B,H,S,HD] ----------------
__global__ __launch_bounds__(256) void gemm_qkv_kernel(
        const float* __restrict__ Xq, const float* __restrict__ Xk, const float* __restrict__ Xv,
        const _Float16* __restrict__ WTall,
        const float* __restrict__ bq, const float* __restrict__ bk, const float* __restrict__ bv,
        _Float16* __restrict__ qo, _Float16* __restrict__ ko2, _Float16* __restrict__ vo) {
    int z = blockIdx.z;
    const float* X = (z == 0) ? Xq : (z == 1) ? Xk : Xv;
    const _Float16* BT = WTall + (size_t)z * 512 * 512;
    const float* bias = (z == 0) ? bq : (z == 1) ? bk : bv;
    _Float16* out = (z == 0) ? qo : (z == 1) ? ko2 : vo;

    __shared__ __align__(16) _Float16 Asm[128][72];
    __shared__ __align__(16) _Float16 Bsm[128][72];

    int tid = threadIdx.x;
    int wave = tid >> 6, lane = tid & 63;
    int lrow = lane & 15, quad = lane >> 4;
    int m0 = (wave >> 1) * 64, n0 = (wave & 1) * 64;
    int mBase = blockIdx.x * 128, nBase = blockIdx.y * 128;

    const floatx4 fz = {0.f, 0.f, 0.f, 0.f};
    floatx4 acc[4][4];
    for (int i = 0; i < 4; i++) for (int j = 0; j < 4; j++) acc[i][j] = fz;

    for (int kb = 0; kb < 512; kb += 64) {
        for (int i = 0; i < 4; i++) {
            int f = i * 256 + tid;
            int row = f >> 3, seg = f & 7;
            *(half8*)&Asm[row][seg * 8] = cvt8(X + (size_t)(mBase + row) * 512 + kb + seg * 8);
            *(half8*)&Bsm[row][seg * 8] = *(const half8*)(BT + (size_t)(nBase + row) * 512 + kb + seg * 8);
        }
        __syncthreads();
        for (int kc = 0; kc < 2; kc++) {
            int ko_ = kc * 32 + quad * 8;
            half8 a[4], b[4];
            for (int mt = 0; mt < 4; mt++) a[mt] = *(const half8*)&Asm[m0 + mt * 16 + lrow][ko_];
            for (int nt = 0; nt < 4; nt++) b[nt] = *(const half8*)&Bsm[n0 + nt * 16 + lrow][ko_];
            for (int mt = 0; mt < 4; mt++)
                for (int nt = 0; nt < 4; nt++)
                    acc[mt][nt] = __builtin_amdgcn_mfma_f32_16x16x32_f16(a[mt], b[nt], acc[mt][nt], 0, 0, 0);
        }
        __syncthreads();
    }

    for (int nt = 0; nt < 4; nt++) {
        int gc = nBase + n0 + nt * 16 + lrow;
        float bb = bias[gc];
        int h = gc >> 6, hd = gc & 63;
        for (int mt = 0; mt < 4; mt++) {
            for (int r = 0; r < 4; r++) {
                int gr = mBase + m0 + mt * 16 + quad * 4 + r;
                int b_ = gr >> 11, s = gr & 2047;
                out[(((size_t)b_ * 8 + h) * 2048 + s) * 64 + hd] = (_Float16)(acc[mt][nt][r] + bb);
            }
        }
    }
}

// ---------------- K3: flash attention, fp16 MFMA, online softmax ----------------
__global__ __launch_bounds__(256) void attn_kernel(
        const _Float16* __restrict__ qws, const _Float16* __restrict__ kws, const _Float16* __restrict__ vws,
        const int* __restrict__ vlens, _Float16* __restrict__ aout) {
    int bh = blockIdx.y;
    int b = bh >> 3, h = bh & 7;
    int q0 = blockIdx.x * 64;
    int L = vlens[b];
    int tid = threadIdx.x;
    int wave = tid >> 6, lane = tid & 63;
    int lrow = lane & 15, quad = lane >> 4;

    __shared__ __align__(16) _Float16 ksm[64][72];
    __shared__ __align__(16) _Float16 vtsm[64][72];
    __shared__ __align__(16) _Float16 psm[4][16][72];

    const _Float16* qbase = qws + ((size_t)bh * 2048 + q0) * 64;
    const _Float16* kbase = kws + (size_t)bh * 2048 * 64;
    const _Float16* vbase = vws + (size_t)bh * 2048 * 64;

    half8 aq[2];
    for (int kc = 0; kc < 2; kc++)
        aq[kc] = *(const half8*)(qbase + (wave * 16 + lrow) * 64 + kc * 32 + quad * 8);

    const floatx4 fz = {0.f, 0.f, 0.f, 0.f};
    floatx4 oacc[4];
    for (int i = 0; i < 4; i++) oacc[i] = fz;
    float mrun[4], lrun[4];
    for (int r = 0; r < 4; r++) { mrun[r] = -INFINITY; lrun[r] = 0.0f; }

    for (int kt = 0; kt < 32; kt++) {
        const _Float16* ktile = kbase + (size_t)kt * 64 * 64;
        const _Float16* vtile = vbase + (size_t)kt * 64 * 64;
        for (int i = 0; i < 2; i++) {
            int f = i * 256 + tid;
            int row = f >> 3, seg = f & 7;
            *(half8*)&ksm[row][seg * 8] = *(const half8*)(ktile + f * 8);
            half8 vv = *(const half8*)(vtile + f * 8);
            for (int j = 0; j < 8; j++) vtsm[seg * 8 + j][row] = vv[j];
        }
        __syncthreads();

        floatx4 sacc[4];
        for (int nt = 0; nt < 4; nt++) sacc[nt] = fz;
        for (int kc = 0; kc < 2; kc++) {
            int ko_ = kc * 32 + quad * 8;
            for (int nt = 0; nt < 4; nt++) {
                half8 bk = *(const half8*)&ksm[nt * 16 + lrow][ko_];
                sacc[nt] = __builtin_amdgcn_mfma_f32_16x16x32_f16(aq[kc], bk, sacc[nt], 0, 0, 0);
            }
        }

        // scale + mask (-1e6 exactly, matching d2l semantics incl. valid_len==0)
        float sv[4][4];
        for (int nt = 0; nt < 4; nt++) {
            int col = kt * 64 + nt * 16 + lrow;
            bool msk = (col >= L);
            for (int r = 0; r < 4; r++)
                sv[nt][r] = msk ? -1.0e6f : sacc[nt][r] * 0.125f;
        }
        // row max across 64 keys (rows live in 16-lane quads)
        float tmax[4];
        for (int r = 0; r < 4; r++) {
            tmax[r] = fmaxf(fmaxf(sv[0][r], sv[1][r]), fmaxf(sv[2][r], sv[3][r]));
            for (int d = 1; d < 16; d <<= 1)
                tmax[r] = fmaxf(tmax[r], __shfl_xor(tmax[r], d, 64));
        }
        float alpha[4], mnew[4], rsum[4];
        for (int r = 0; r < 4; r++) {
            mnew[r] = fmaxf(mrun[r], tmax[r]);
            alpha[r] = exp2f((mrun[r] - mnew[r]) * LOG2E);
            mrun[r] = mnew[r];
            rsum[r] = 0.0f;
        }
        for (int nt = 0; nt < 4; nt++) {
            for (int r = 0; r < 4; r++) {
                float p = exp2f((sv[nt][r] - mnew[r]) * LOG2E);
                rsum[r] += p;
                psm[wave][quad * 4 + r][nt * 16 + lrow] = (_Float16)p;
            }
        }
        for (int r = 0; r < 4; r++) {
            for (int d = 1; d < 16; d <<= 1)
                rsum[r] += __shfl_xor(rsum[r], d, 64);
            lrun[r] = lrun[r] * alpha[r] + rsum[r];
        }
        for (int nt = 0; nt < 4; nt++)
            for (int r = 0; r < 4; r++)
                oacc[nt][r] *= alpha[r];
        __syncthreads();   // psm C-layout -> A-layout round trip

        for (int kc = 0; kc < 2; kc++) {
            int ko_ = kc * 32 + quad * 8;
            half8 ap = *(const half8*)&psm[wave][lrow][ko_];
            for (int nt = 0; nt < 4; nt++) {
                half8 bv = *(const half8*)&vtsm[nt * 16 + lrow][ko_];
                oacc[nt] = __builtin_amdgcn_mfma_f32_16x16x32_f16(ap, bv, oacc[nt], 0, 0, 0);
            }
        }
        __syncthreads();
    }

    float inv[4];
    for (int r = 0; r < 4; r++) inv[r] = 1.0f / lrun[r];
    int srow_base = q0 + wave * 16 + quad * 4;
    for (int nt = 0; nt < 4; nt++) {
        for (int r = 0; r < 4; r++) {
            int s = srow_base + r;
            aout[((size_t)b * 2048 + s) * 512 + h * 64 + nt * 16 + lrow] = (_Float16)(oacc[nt][r] * inv[r]);
        }
    }
}

// ---------------- K4: output projection: attn_out(fp16) @ Wo + bo -> f32 ----------------
__global__ __launch_bounds__(256) void gemm_out_kernel(
        const _Float16* __restrict__ A, const _Float16* __restrict__ BT,
        const float* __restrict__ bias, float* __restrict__ out) {
    __shared__ __align__(16) _Float16 Asm[128][72];
    __shared__ __align__(16) _Float16 Bsm[128][72];

    int tid = threadIdx.x;
    int wave = tid >> 6, lane = tid & 63;
    int lrow = lane & 15, quad = lane >> 4;
    int m0 = (wave >> 1) * 64, n0 = (wave & 1) * 64;
    int mBase = blockIdx.x * 128, nBase = blockIdx.y * 128;

    const floatx4 fz = {0.f, 0.f, 0.f, 0.f};
    floatx4 acc[4][4];
    for (int i = 0; i < 4; i++) for (int j = 0; j < 4; j++) acc[i][j] = fz;

    for (int kb = 0; kb < 512; kb += 64) {
        for (int i = 0; i < 4; i++) {
            int f = i * 256 + tid;
            int row = f >> 3, seg = f & 7;
            *(half8*)&Asm[row][seg * 8] = *(const half8*)(A + (size_t)(mBase + row) * 512 + kb + seg * 8);
            *(half8*)&Bsm[row][seg * 8] = *(const half8*)(BT + (size_t)(nBase + row) * 512 + kb + seg * 8);
        }
        __syncthreads();
        for (int kc = 0; kc < 2; kc++) {
            int ko_ = kc * 32 + quad * 8;
            half8 a[4], b[4];
            for (int mt = 0; mt < 4; mt++) a[mt] = *(const half8*)&Asm[m0 + mt * 16 + lrow][ko_];
            for (int nt = 0; nt < 4; nt++) b[nt] = *(const half8*)&Bsm[n0 + nt * 16 + lrow][ko_];
            for (int mt = 0; mt < 4; mt++)
                for (int nt = 0; nt < 4; nt++)
                    acc[mt][nt] = __builtin_amdgcn_mfma_f32_16x16x32_f16(a[mt], b[nt], acc[mt][nt], 0, 0, 0);
        }
        __syncthreads();
    }

    for (int nt = 0; nt < 4; nt++) {
        int gc = nBase + n0 + nt * 16 + lrow;
        float bb = bias[gc];
        for (int mt = 0; mt < 4; mt++) {
            for (int r = 0; r < 4; r++) {
                int gr = mBase + m0 + mt * 16 + quad * 4 + r;
                out[(size_t)gr * 512 + gc] = acc[mt][nt][r] + bb;
            }
        }
    }
}

extern "C" void kernel_launch(void* const* d_in, const int* in_sizes, int n_in,
                              void* d_out, int out_size, void* d_ws, size_t ws_size,
                              hipStream_t stream) {
    const float* Q  = (const float*)d_in[0];
    const float* K  = (const float*)d_in[1];
    const float* V  = (const float*)d_in[2];
    const int*   VL = (const int*)d_in[3];
    const float* Wq = (const float*)d_in[4];
    const float* bq = (const float*)d_in[5];
    const float* Wk = (const float*)d_in[6];
    const float* bk = (const float*)d_in[7];
    const float* Wv = (const float*)d_in[8];
    const float* bv = (const float*)d_in[9];
    const float* Wo = (const float*)d_in[10];
    const float* bo = (const float*)d_in[11];

    char* ws = (char*)d_ws;
    _Float16* WT   = (_Float16*)ws;                                  // 4 x 512x512 fp16 = 2 MiB
    _Float16* qws  = (_Float16*)(ws + (size_t)(2)  * 1024 * 1024);   // 8 MiB  [B,H,S,HD]
    _Float16* kws  = (_Float16*)(ws + (size_t)(10) * 1024 * 1024);   // 8 MiB
    _Float16* vws  = (_Float16*)(ws + (size_t)(18) * 1024 * 1024);   // 8 MiB
    _Float16* aout = (_Float16*)(ws + (size_t)(26) * 1024 * 1024);   // 8 MiB  [8192,512]

    transpose_w_kernel<<<dim3(8, 8, 4), 256, 0, stream>>>(Wq, Wk, Wv, Wo, WT);
    gemm_qkv_kernel<<<dim3(64, 4, 3), 256, 0, stream>>>(Q, K, V, WT, bq, bk, bv, qws, kws, vws);
    attn_kernel<<<dim3(32, 32, 1), 256, 0, stream>>>(qws, kws, vws, VL, aout);
    gemm_out_kernel<<<dim3(64, 4, 1), 256, 0, stream>>>(aout, WT + (size_t)3 * 512 * 512, bo, (float*)d_out);
}

// Round 3
// 226.892 us; speedup vs baseline: 1.4495x; 1.4495x over previous
//
#include <hip/hip_runtime.h>
#include <hip/hip_bf16.h>

typedef _Float16 half8 __attribute__((ext_vector_type(8)));
typedef float floatx4 __attribute__((ext_vector_type(4)));

#define LOG2E 1.44269504088896340736f

__device__ __forceinline__ half8 cvt8(const float* p) {
    floatx4 a = *(const floatx4*)p;
    floatx4 b = *(const floatx4*)(p + 4);
    half8 h;
    h[0] = (_Float16)a[0]; h[1] = (_Float16)a[1]; h[2] = (_Float16)a[2]; h[3] = (_Float16)a[3];
    h[4] = (_Float16)b[0]; h[5] = (_Float16)b[1]; h[6] = (_Float16)b[2]; h[7] = (_Float16)b[3];
    return h;
}

// ---------------- K1: transpose + convert W (f32 [512x512]) -> WT fp16 [n][k] ----------------
__global__ __launch_bounds__(256) void transpose_w_kernel(
        const float* __restrict__ Wq, const float* __restrict__ Wk,
        const float* __restrict__ Wv, const float* __restrict__ Wo,
        _Float16* __restrict__ out) {
    const float* W = (blockIdx.z == 0) ? Wq : (blockIdx.z == 1) ? Wk : (blockIdx.z == 2) ? Wv : Wo;
    _Float16* o = out + (size_t)blockIdx.z * 512 * 512;
    __shared__ __align__(16) _Float16 t[64][72];
    int r0 = blockIdx.x * 64, c0 = blockIdx.y * 64;
    int tid = threadIdx.x;
    for (int i = 0; i < 2; i++) {
        int f = i * 256 + tid;
        int row = f >> 3, seg = f & 7;
        *(half8*)&t[row][seg * 8] = cvt8(W + (size_t)(r0 + row) * 512 + c0 + seg * 8);
    }
    __syncthreads();
    for (int i = 0; i < 2; i++) {
        int f = i * 256 + tid;
        int crow = f >> 3, seg = f & 7;
        half8 hv;
        for (int j = 0; j < 8; j++) hv[j] = t[seg * 8 + j][crow];
        *(half8*)(o + (size_t)(c0 + crow) * 512 + r0 + seg * 8) = hv;
    }
}

// ---------------- K2: QKV projection GEMM: C = X(f32->fp16) @ W + b -> fp16 [B,H,S,HD] ----------------
__global__ __launch_bounds__(256) void gemm_qkv_kernel(
        const float* __restrict__ Xq, const float* __restrict__ Xk, const float* __restrict__ Xv,
        const _Float16* __restrict__ WTall,
        const float* __restrict__ bq, const float* __restrict__ bk, const float* __restrict__ bv,
        _Float16* __restrict__ qo, _Float16* __restrict__ ko2, _Float16* __restrict__ vo) {
    int z = blockIdx.z;
    const float* X = (z == 0) ? Xq : (z == 1) ? Xk : Xv;
    const _Float16* BT = WTall + (size_t)z * 512 * 512;
    const float* bias = (z == 0) ? bq : (z == 1) ? bk : bv;
    _Float16* out = (z == 0) ? qo : (z == 1) ? ko2 : vo;

    __shared__ __align__(16) _Float16 Asm[128][72];
    __shared__ __align__(16) _Float16 Bsm[128][72];

    int tid = threadIdx.x;
    int wave = tid >> 6, lane = tid & 63;
    int lrow = lane & 15, quad = lane >> 4;
    int m0 = (wave >> 1) * 64, n0 = (wave & 1) * 64;
    int mBase = blockIdx.x * 128, nBase = blockIdx.y * 128;

    const floatx4 fz = {0.f, 0.f, 0.f, 0.f};
    floatx4 acc[4][4];
    for (int i = 0; i < 4; i++) for (int j = 0; j < 4; j++) acc[i][j] = fz;

    for (int kb = 0; kb < 512; kb += 64) {
        for (int i = 0; i < 4; i++) {
            int f = i * 256 + tid;
            int row = f >> 3, seg = f & 7;
            *(half8*)&Asm[row][seg * 8] = cvt8(X + (size_t)(mBase + row) * 512 + kb + seg * 8);
            *(half8*)&Bsm[row][seg * 8] = *(const half8*)(BT + (size_t)(nBase + row) * 512 + kb + seg * 8);
        }
        __syncthreads();
        for (int kc = 0; kc < 2; kc++) {
            int ko_ = kc * 32 + quad * 8;
            half8 a[4], b[4];
            for (int mt = 0; mt < 4; mt++) a[mt] = *(const half8*)&Asm[m0 + mt * 16 + lrow][ko_];
            for (int nt = 0; nt < 4; nt++) b[nt] = *(const half8*)&Bsm[n0 + nt * 16 + lrow][ko_];
            for (int mt = 0; mt < 4; mt++)
                for (int nt = 0; nt < 4; nt++)
                    acc[mt][nt] = __builtin_amdgcn_mfma_f32_16x16x32_f16(a[mt], b[nt], acc[mt][nt], 0, 0, 0);
        }
        __syncthreads();
    }

    for (int nt = 0; nt < 4; nt++) {
        int gc = nBase + n0 + nt * 16 + lrow;
        float bb = bias[gc];
        int h = gc >> 6, hd = gc & 63;
        for (int mt = 0; mt < 4; mt++) {
            for (int r = 0; r < 4; r++) {
                int gr = mBase + m0 + mt * 16 + quad * 4 + r;
                int b_ = gr >> 11, s = gr & 2047;
                out[(((size_t)b_ * 8 + h) * 2048 + s) * 64 + hd] = (_Float16)(acc[mt][nt][r] + bb);
            }
        }
    }
}

// ---------------- K2b: transpose V: [bh][s][hd] -> VT [bh][hd][s] ----------------
__global__ __launch_bounds__(256) void transpose_v_kernel(
        const _Float16* __restrict__ v, _Float16* __restrict__ vt) {
    int bh = blockIdx.z;
    int s0 = blockIdx.x * 64;
    __shared__ __align__(16) _Float16 t[64][72];
    int tid = threadIdx.x;
    for (int i = 0; i < 2; i++) {
        int f = i * 256 + tid;
        int row = f >> 3, seg = f & 7;
        *(half8*)&t[row][seg * 8] = *(const half8*)(v + ((size_t)bh * 2048 + s0 + row) * 64 + seg * 8);
    }
    __syncthreads();
    for (int i = 0; i < 2; i++) {
        int f = i * 256 + tid;
        int crow = f >> 3, seg = f & 7;   // crow = hd, seg*8 = s offset
        half8 hv;
        for (int j = 0; j < 8; j++) hv[j] = t[seg * 8 + j][crow];
        *(half8*)(vt + ((size_t)bh * 64 + crow) * 2048 + s0 + seg * 8) = hv;
    }
}

// ---------------- K3: flash attention v2: fixed-max softmax, early exit, ones-column sums ----------------
// BM=128 (4 waves x 32 rows), BN=64. V^T pre-transposed. 2 barriers/tile.
__global__ __launch_bounds__(256) void attn_kernel(
        const _Float16* __restrict__ qws, const _Float16* __restrict__ kws, const _Float16* __restrict__ vtws,
        const int* __restrict__ vlens, _Float16* __restrict__ aout) {
    int bh = blockIdx.y;
    int b = bh >> 3, h = bh & 7;
    int q0 = blockIdx.x * 128;
    int L = vlens[b];
    bool uni = (L == 0);                  // all masked -> uniform softmax (d2l -1e6 semantics)
    int nkt = uni ? 32 : ((L + 63) >> 6); // masked keys contribute exactly 0 -> skip their tiles
    int tid = threadIdx.x;
    int wave = tid >> 6, lane = tid & 63;
    int lrow = lane & 15, quad = lane >> 4;

    __shared__ __align__(16) _Float16 ksm[64][72];
    __shared__ __align__(16) _Float16 vtsm[80][72];      // rows 0..63: V^T tile; 64: ones; 65..79: zeros
    __shared__ __align__(16) _Float16 psm[4][2][16][72]; // [wave][mt][row][key]

    // init ones/zero rows of vtsm (once; covered by first staging barrier)
    for (int i = tid; i < 16 * 36; i += 256) {
        int r = i / 36, c = i % 36;
        ((float*)&vtsm[64 + r][0])[c] = 0.0f;
    }
    if (tid < 64) vtsm[64][tid] = (_Float16)1.0f;

    const _Float16* qbase = qws + ((size_t)bh * 2048 + q0) * 64;
    const _Float16* kbase = kws + (size_t)bh * 2048 * 64;
    const _Float16* vtbase = vtws + (size_t)bh * 64 * 2048;

    half8 aq[2][2];
    for (int mt = 0; mt < 2; mt++)
        for (int kc = 0; kc < 2; kc++)
            aq[mt][kc] = *(const half8*)(qbase + (wave * 32 + mt * 16 + lrow) * 64 + kc * 32 + quad * 8);

    const floatx4 fz = {0.f, 0.f, 0.f, 0.f};
    floatx4 oacc[2][5];
    for (int mt = 0; mt < 2; mt++) for (int nt = 0; nt < 5; nt++) oacc[mt][nt] = fz;

    const float cexp = 0.125f * LOG2E;   // fold 1/sqrt(64) into exp2 constant

    for (int kt = 0; kt < nkt; kt++) {
        const _Float16* ktile = kbase + (size_t)kt * 64 * 64;           // contiguous [64][64]
        const _Float16* vttile = vtbase + kt * 64;                      // rows stride 2048
        for (int i = 0; i < 2; i++) {
            int f = i * 256 + tid;
            int row = f >> 3, seg = f & 7;
            *(half8*)&ksm[row][seg * 8] = *(const half8*)(ktile + f * 8);
            *(half8*)&vtsm[row][seg * 8] = *(const half8*)(vttile + (size_t)row * 2048 + seg * 8);
        }
        __syncthreads();

        floatx4 sacc[2][4];
        for (int mt = 0; mt < 2; mt++) for (int nt = 0; nt < 4; nt++) sacc[mt][nt] = fz;
        for (int kc = 0; kc < 2; kc++) {
            int ko_ = kc * 32 + quad * 8;
            half8 bk[4];
            for (int nt = 0; nt < 4; nt++) bk[nt] = *(const half8*)&ksm[nt * 16 + lrow][ko_];
            for (int mt = 0; mt < 2; mt++)
                for (int nt = 0; nt < 4; nt++)
                    sacc[mt][nt] = __builtin_amdgcn_mfma_f32_16x16x32_f16(aq[mt][kc], bk[nt], sacc[mt][nt], 0, 0, 0);
        }

        // p = exp(s/8) for valid cols, 0 for masked, 1 if fully-masked batch (uniform)
        for (int nt = 0; nt < 4; nt++) {
            int col = kt * 64 + nt * 16 + lrow;
            bool valid = col < L;
            for (int mt = 0; mt < 2; mt++) {
                for (int r = 0; r < 4; r++) {
                    float p = uni ? 1.0f : (valid ? exp2f(sacc[mt][nt][r] * cexp) : 0.0f);
                    psm[wave][mt][quad * 4 + r][nt * 16 + lrow] = (_Float16)p;
                }
            }
        }
        // psm is wave-private: no barrier needed (compiler orders via lgkmcnt)

        for (int kc = 0; kc < 2; kc++) {
            int ko_ = kc * 32 + quad * 8;
            half8 ap[2];
            for (int mt = 0; mt < 2; mt++) ap[mt] = *(const half8*)&psm[wave][mt][lrow][ko_];
            for (int nt = 0; nt < 5; nt++) {           // nt==4: ones column -> row sums
                half8 bv = *(const half8*)&vtsm[nt * 16 + lrow][ko_];
                for (int mt = 0; mt < 2; mt++)
                    oacc[mt][nt] = __builtin_amdgcn_mfma_f32_16x16x32_f16(ap[mt], bv, oacc[mt][nt], 0, 0, 0);
            }
        }
        __syncthreads();
    }

    // row sums live in oacc[mt][4], C-layout col 0 -> lane (quad*16); broadcast within quad
    float inv[2][4];
    for (int mt = 0; mt < 2; mt++)
        for (int r = 0; r < 4; r++)
            inv[mt][r] = 1.0f / __shfl(oacc[mt][4][r], (lane & 48), 64);

    for (int mt = 0; mt < 2; mt++) {
        for (int nt = 0; nt < 4; nt++) {
            for (int r = 0; r < 4; r++) {
                int s = q0 + wave * 32 + mt * 16 + quad * 4 + r;
                aout[((size_t)b * 2048 + s) * 512 + h * 64 + nt * 16 + lrow] =
                    (_Float16)(oacc[mt][nt][r] * inv[mt][r]);
            }
        }
    }
}

// ---------------- K4: output projection: attn_out(fp16) @ Wo + bo -> f32 ----------------
__global__ __launch_bounds__(256) void gemm_out_kernel(
        const _Float16* __restrict__ A, const _Float16* __restrict__ BT,
        const float* __restrict__ bias, float* __restrict__ out) {
    __shared__ __align__(16) _Float16 Asm[128][72];
    __shared__ __align__(16) _Float16 Bsm[128][72];

    int tid = threadIdx.x;
    int wave = tid >> 6, lane = tid & 63;
    int lrow = lane & 15, quad = lane >> 4;
    int m0 = (wave >> 1) * 64, n0 = (wave & 1) * 64;
    int mBase = blockIdx.x * 128, nBase = blockIdx.y * 128;

    const floatx4 fz = {0.f, 0.f, 0.f, 0.f};
    floatx4 acc[4][4];
    for (int i = 0; i < 4; i++) for (int j = 0; j < 4; j++) acc[i][j] = fz;

    for (int kb = 0; kb < 512; kb += 64) {
        for (int i = 0; i < 4; i++) {
            int f = i * 256 + tid;
            int row = f >> 3, seg = f & 7;
            *(half8*)&Asm[row][seg * 8] = *(const half8*)(A + (size_t)(mBase + row) * 512 + kb + seg * 8);
            *(half8*)&Bsm[row][seg * 8] = *(const half8*)(BT + (size_t)(nBase + row) * 512 + kb + seg * 8);
        }
        __syncthreads();
        for (int kc = 0; kc < 2; kc++) {
            int ko_ = kc * 32 + quad * 8;
            half8 a[4], b[4];
            for (int mt = 0; mt < 4; mt++) a[mt] = *(const half8*)&Asm[m0 + mt * 16 + lrow][ko_];
            for (int nt = 0; nt < 4; nt++) b[nt] = *(const half8*)&Bsm[n0 + nt * 16 + lrow][ko_];
            for (int mt = 0; mt < 4; mt++)
                for (int nt = 0; nt < 4; nt++)
                    acc[mt][nt] = __builtin_amdgcn_mfma_f32_16x16x32_f16(a[mt], b[nt], acc[mt][nt], 0, 0, 0);
        }
        __syncthreads();
    }

    for (int nt = 0; nt < 4; nt++) {
        int gc = nBase + n0 + nt * 16 + lrow;
        float bb = bias[gc];
        for (int mt = 0; mt < 4; mt++) {
            for (int r = 0; r < 4; r++) {
                int gr = mBase + m0 + mt * 16 + quad * 4 + r;
                out[(size_t)gr * 512 + gc] = acc[mt][nt][r] + bb;
            }
        }
    }
}

extern "C" void kernel_launch(void* const* d_in, const int* in_sizes, int n_in,
                              void* d_out, int out_size, void* d_ws, size_t ws_size,
                              hipStream_t stream) {
    const float* Q  = (const float*)d_in[0];
    const float* K  = (const float*)d_in[1];
    const float* V  = (const float*)d_in[2];
    const int*   VL = (const int*)d_in[3];
    const float* Wq = (const float*)d_in[4];
    const float* bq = (const float*)d_in[5];
    const float* Wk = (const float*)d_in[6];
    const float* bk = (const float*)d_in[7];
    const float* Wv = (const float*)d_in[8];
    const float* bv = (const float*)d_in[9];
    const float* Wo = (const float*)d_in[10];
    const float* bo = (const float*)d_in[11];

    char* ws = (char*)d_ws;
    _Float16* WT   = (_Float16*)ws;                                  // 2 MiB: 4 x 512x512 fp16
    _Float16* qws  = (_Float16*)(ws + (size_t)(2)  * 1024 * 1024);   // 8 MiB  [B,H,S,HD]
    _Float16* kws  = (_Float16*)(ws + (size_t)(10) * 1024 * 1024);   // 8 MiB
    _Float16* vws  = (_Float16*)(ws + (size_t)(18) * 1024 * 1024);   // 8 MiB  (aliased by aout below)
    _Float16* vtws = (_Float16*)(ws + (size_t)(26) * 1024 * 1024);   // 8 MiB  [bh][hd][s]
    _Float16* aout = vws;  // safe alias: vws consumed by transpose_v before attn writes aout

    transpose_w_kernel<<<dim3(8, 8, 4), 256, 0, stream>>>(Wq, Wk, Wv, Wo, WT);
    gemm_qkv_kernel<<<dim3(64, 4, 3), 256, 0, stream>>>(Q, K, V, WT, bq, bk, bv, qws, kws, vws);
    transpose_v_kernel<<<dim3(32, 1, 32), 256, 0, stream>>>(vws, vtws);
    attn_kernel<<<dim3(16, 32, 1), 256, 0, stream>>>(qws, kws, vtws, VL, aout);
    gemm_out_kernel<<<dim3(64, 4, 1), 256, 0, stream>>>(aout, WT + (size_t)3 * 512 * 512, bo, (float*)d_out);
}

// Round 5
// 206.929 us; speedup vs baseline: 1.5893x; 1.0965x over previous
//
#include <hip/hip_runtime.h>
#include <hip/hip_bf16.h>

typedef _Float16 half8 __attribute__((ext_vector_type(8)));
typedef _Float16 half4 __attribute__((ext_vector_type(4)));
typedef float floatx4 __attribute__((ext_vector_type(4)));

#define LOG2E 1.44269504088896340736f

__device__ __forceinline__ half8 cvt8(const float* p) {
    floatx4 a = *(const floatx4*)p;
    floatx4 b = *(const floatx4*)(p + 4);
    half8 h;
    h[0] = (_Float16)a[0]; h[1] = (_Float16)a[1]; h[2] = (_Float16)a[2]; h[3] = (_Float16)a[3];
    h[4] = (_Float16)b[0]; h[5] = (_Float16)b[1]; h[6] = (_Float16)b[2]; h[7] = (_Float16)b[3];
    return h;
}

// ---------------- K1: transpose + convert W (f32 [512x512]) -> WT fp16 [n][k] ----------------
__global__ __launch_bounds__(256) void transpose_w_kernel(
        const float* __restrict__ Wq, const float* __restrict__ Wk,
        const float* __restrict__ Wv, const float* __restrict__ Wo,
        _Float16* __restrict__ out) {
    const float* W = (blockIdx.z == 0) ? Wq : (blockIdx.z == 1) ? Wk : (blockIdx.z == 2) ? Wv : Wo;
    _Float16* o = out + (size_t)blockIdx.z * 512 * 512;
    __shared__ __align__(16) _Float16 t[64][72];
    int r0 = blockIdx.x * 64, c0 = blockIdx.y * 64;
    int tid = threadIdx.x;
    for (int i = 0; i < 2; i++) {
        int f = i * 256 + tid;
        int row = f >> 3, seg = f & 7;
        *(half8*)&t[row][seg * 8] = cvt8(W + (size_t)(r0 + row) * 512 + c0 + seg * 8);
    }
    __syncthreads();
    for (int i = 0; i < 2; i++) {
        int f = i * 256 + tid;
        int crow = f >> 3, seg = f & 7;
        half8 hv;
        for (int j = 0; j < 8; j++) hv[j] = t[seg * 8 + j][crow];
        *(half8*)(o + (size_t)(c0 + crow) * 512 + r0 + seg * 8) = hv;
    }
}

// ---------------- K2: QKV projection GEMM; V written pre-transposed [bh][hd][s] ----------------
__global__ __launch_bounds__(256) void gemm_qkv_kernel(
        const float* __restrict__ Xq, const float* __restrict__ Xk, const float* __restrict__ Xv,
        const _Float16* __restrict__ WTall,
        const float* __restrict__ bq, const float* __restrict__ bk, const float* __restrict__ bv,
        _Float16* __restrict__ qo, _Float16* __restrict__ ko2, _Float16* __restrict__ vto) {
    int z = blockIdx.z;
    const float* X = (z == 0) ? Xq : (z == 1) ? Xk : Xv;
    const _Float16* BT = WTall + (size_t)z * 512 * 512;
    const float* bias = (z == 0) ? bq : (z == 1) ? bk : bv;

    __shared__ __align__(16) _Float16 Asm[128][72];
    __shared__ __align__(16) _Float16 Bsm[128][72];

    int tid = threadIdx.x;
    int wave = tid >> 6, lane = tid & 63;
    int lrow = lane & 15, quad = lane >> 4;
    int m0 = (wave >> 1) * 64, n0 = (wave & 1) * 64;
    int mBase = blockIdx.x * 128, nBase = blockIdx.y * 128;

    const floatx4 fz = {0.f, 0.f, 0.f, 0.f};
    floatx4 acc[4][4];
    for (int i = 0; i < 4; i++) for (int j = 0; j < 4; j++) acc[i][j] = fz;

    for (int kb = 0; kb < 512; kb += 64) {
        for (int i = 0; i < 4; i++) {
            int f = i * 256 + tid;
            int row = f >> 3, seg = f & 7;
            *(half8*)&Asm[row][seg * 8] = cvt8(X + (size_t)(mBase + row) * 512 + kb + seg * 8);
            *(half8*)&Bsm[row][seg * 8] = *(const half8*)(BT + (size_t)(nBase + row) * 512 + kb + seg * 8);
        }
        __syncthreads();
        for (int kc = 0; kc < 2; kc++) {
            int ko_ = kc * 32 + quad * 8;
            half8 a[4], b[4];
            for (int mt = 0; mt < 4; mt++) a[mt] = *(const half8*)&Asm[m0 + mt * 16 + lrow][ko_];
            for (int nt = 0; nt < 4; nt++) b[nt] = *(const half8*)&Bsm[n0 + nt * 16 + lrow][ko_];
            for (int mt = 0; mt < 4; mt++)
                for (int nt = 0; nt < 4; nt++)
                    acc[mt][nt] = __builtin_amdgcn_mfma_f32_16x16x32_f16(a[mt], b[nt], acc[mt][nt], 0, 0, 0);
        }
        __syncthreads();
    }

    if (z == 2) {
        // V: write transposed [bh][hd][s], packed half4 along s
        for (int nt = 0; nt < 4; nt++) {
            int gc = nBase + n0 + nt * 16 + lrow;
            float bb = bias[gc];
            int h = gc >> 6, hd = gc & 63;
            for (int mt = 0; mt < 4; mt++) {
                int gr = mBase + m0 + mt * 16 + quad * 4;
                int b_ = gr >> 11, s = gr & 2047;
                half4 hv;
                for (int r = 0; r < 4; r++) hv[r] = (_Float16)(acc[mt][nt][r] + bb);
                *(half4*)(vto + (((size_t)(b_ * 8 + h) * 64 + hd) * 2048 + s)) = hv;
            }
        }
    } else {
        _Float16* out = (z == 0) ? qo : ko2;
        for (int nt = 0; nt < 4; nt++) {
            int gc = nBase + n0 + nt * 16 + lrow;
            float bb = bias[gc];
            int h = gc >> 6, hd = gc & 63;
            for (int mt = 0; mt < 4; mt++) {
                for (int r = 0; r < 4; r++) {
                    int gr = mBase + m0 + mt * 16 + quad * 4 + r;
                    int b_ = gr >> 11, s = gr & 2047;
                    out[(((size_t)b_ * 8 + h) * 2048 + s) * 64 + hd] = (_Float16)(acc[mt][nt][r] + bb);
                }
            }
        }
    }
}

// ---------------- K3: flash attention v3: S^T trick, P stays in registers ----------------
// BM=64 (4 waves x 16 q-rows), BN=64. QK^T computed as S^T=mfma(K,Q) so its C-layout
// equals the A-layout of mfma_16x16x16 for PV. grid 1024, b-swizzled for balance.
__global__ __launch_bounds__(256) void attn_kernel(
        const _Float16* __restrict__ qws, const _Float16* __restrict__ kws, const _Float16* __restrict__ vtws,
        const int* __restrict__ vlens, _Float16* __restrict__ aout) {
    int idx = blockIdx.x;
    int b = ((idx & 3) + (idx >> 8)) & 3;     // batch varies fastest AND across idx+256k
    int h = (idx >> 2) & 7;
    int q0 = ((idx >> 5) & 31) * 64;
    int bh = b * 8 + h;
    int L = vlens[b];
    bool uni = (L == 0);                      // fully masked -> uniform softmax
    int nkt = uni ? 32 : ((L + 63) >> 6);     // masked keys contribute exactly 0 -> skip
    int tid = threadIdx.x;
    int wave = tid >> 6, lane = tid & 63;
    int lrow = lane & 15, quad = lane >> 4;

    __shared__ __align__(16) _Float16 ksm[64][72];
    __shared__ __align__(16) _Float16 vtsm[80][72];  // rows 0..63: V^T (hd,key); 64: ones; 65..79: zeros

    for (int i = tid; i < 15 * 36; i += 256) {       // zero rows 65..79
        int r = i / 36, c = i % 36;
        ((float*)&vtsm[65 + r][0])[c] = 0.0f;
    }
    if (tid < 64) vtsm[64][tid] = (_Float16)1.0f;    // ones row (row-sum column); [64..71] never read

    const _Float16* qbase = qws + ((size_t)bh * 2048 + q0) * 64;
    const _Float16* kbase = kws + (size_t)bh * 2048 * 64;
    const _Float16* vtbase = vtws + (size_t)bh * 64 * 2048;

    half8 qf[2];   // B-operand fragments: n=q=lrow, k=d
    for (int kc = 0; kc < 2; kc++)
        qf[kc] = *(const half8*)(qbase + (wave * 16 + lrow) * 64 + kc * 32 + quad * 8);

    const floatx4 fz = {0.f, 0.f, 0.f, 0.f};
    floatx4 oacc[5];                                 // nt=4: ones column -> row sums
    for (int nt = 0; nt < 5; nt++) oacc[nt] = fz;
    const float cexp = 0.125f * LOG2E;

    for (int kt = 0; kt < nkt; kt++) {
        const _Float16* ktile = kbase + (size_t)kt * 64 * 64;
        const _Float16* vttile = vtbase + kt * 64;
        for (int i = 0; i < 2; i++) {
            int f = i * 256 + tid;
            int row = f >> 3, seg = f & 7;
            *(half8*)&ksm[row][seg * 8] = *(const half8*)(ktile + f * 8);
            *(half8*)&vtsm[row][seg * 8] = *(const half8*)(vttile + (size_t)row * 2048 + seg * 8);
        }
        __syncthreads();

        // S^T: m=key (4 subtiles), n=q (wave's 16 rows)
        floatx4 sacc[4];
        for (int km = 0; km < 4; km++) sacc[km] = fz;
        for (int kc = 0; kc < 2; kc++) {
            int ko_ = kc * 32 + quad * 8;
            for (int km = 0; km < 4; km++) {
                half8 kf = *(const half8*)&ksm[km * 16 + lrow][ko_];
                sacc[km] = __builtin_amdgcn_mfma_f32_16x16x32_f16(kf, qf[kc], sacc[km], 0, 0, 0);
            }
        }

        // exp in-register; sacc C-layout (key=km*16+quad*4+r, q=lrow) IS the PV A-layout
        half4 pf[4];
        int kb0 = kt * 64 + quad * 4;
        for (int km = 0; km < 4; km++) {
            int kb = kb0 + km * 16;
            for (int r = 0; r < 4; r++) {
                float p = uni ? 1.0f : ((kb + r < L) ? exp2f(sacc[km][r] * cexp) : 0.0f);
                pf[km][r] = (_Float16)p;
            }
        }

        // PV: D[q][hd] += P[q][key16] * V[key16][hd], K=16 per step (legacy mfma, no underscore)
        for (int km = 0; km < 4; km++) {
            int kk = km * 16 + quad * 4;
            for (int nt = 0; nt < 5; nt++) {
                half4 bvf = *(const half4*)&vtsm[nt * 16 + lrow][kk];
                oacc[nt] = __builtin_amdgcn_mfma_f32_16x16x16f16(pf[km], bvf, oacc[nt], 0, 0, 0);
            }
        }
        __syncthreads();
    }

    // row sums at col 0 of nt=4 tile: lane quad*16 holds sums for rows quad*4+r
    float inv[4];
    for (int r = 0; r < 4; r++)
        inv[r] = 1.0f / __shfl(oacc[4][r], quad << 4, 64);

    for (int nt = 0; nt < 4; nt++) {
        for (int r = 0; r < 4; r++) {
            int s = q0 + wave * 16 + quad * 4 + r;
            aout[((size_t)b * 2048 + s) * 512 + h * 64 + nt * 16 + lrow] =
                (_Float16)(oacc[nt][r] * inv[r]);
        }
    }
}

// ---------------- K4: output projection: attn_out(fp16) @ Wo + bo -> f32 ----------------
__global__ __launch_bounds__(256) void gemm_out_kernel(
        const _Float16* __restrict__ A, const _Float16* __restrict__ BT,
        const float* __restrict__ bias, float* __restrict__ out) {
    __shared__ __align__(16) _Float16 Asm[128][72];
    __shared__ __align__(16) _Float16 Bsm[128][72];

    int tid = threadIdx.x;
    int wave = tid >> 6, lane = tid & 63;
    int lrow = lane & 15, quad = lane >> 4;
    int m0 = (wave >> 1) * 64, n0 = (wave & 1) * 64;
    int mBase = blockIdx.x * 128, nBase = blockIdx.y * 128;

    const floatx4 fz = {0.f, 0.f, 0.f, 0.f};
    floatx4 acc[4][4];
    for (int i = 0; i < 4; i++) for (int j = 0; j < 4; j++) acc[i][j] = fz;

    for (int kb = 0; kb < 512; kb += 64) {
        for (int i = 0; i < 4; i++) {
            int f = i * 256 + tid;
            int row = f >> 3, seg = f & 7;
            *(half8*)&Asm[row][seg * 8] = *(const half8*)(A + (size_t)(mBase + row) * 512 + kb + seg * 8);
            *(half8*)&Bsm[row][seg * 8] = *(const half8*)(BT + (size_t)(nBase + row) * 512 + kb + seg * 8);
        }
        __syncthreads();
        for (int kc = 0; kc < 2; kc++) {
            int ko_ = kc * 32 + quad * 8;
            half8 a[4], b[4];
            for (int mt = 0; mt < 4; mt++) a[mt] = *(const half8*)&Asm[m0 + mt * 16 + lrow][ko_];
            for (int nt = 0; nt < 4; nt++) b[nt] = *(const half8*)&Bsm[n0 + nt * 16 + lrow][ko_];
            for (int mt = 0; mt < 4; mt++)
                for (int nt = 0; nt < 4; nt++)
                    acc[mt][nt] = __builtin_amdgcn_mfma_f32_16x16x32_f16(a[mt], b[nt], acc[mt][nt], 0, 0, 0);
        }
        __syncthreads();
    }

    for (int nt = 0; nt < 4; nt++) {
        int gc = nBase + n0 + nt * 16 + lrow;
        float bb = bias[gc];
        for (int mt = 0; mt < 4; mt++) {
            for (int r = 0; r < 4; r++) {
                int gr = mBase + m0 + mt * 16 + quad * 4 + r;
                out[(size_t)gr * 512 + gc] = acc[mt][nt][r] + bb;
            }
        }
    }
}

extern "C" void kernel_launch(void* const* d_in, const int* in_sizes, int n_in,
                              void* d_out, int out_size, void* d_ws, size_t ws_size,
                              hipStream_t stream) {
    const float* Q  = (const float*)d_in[0];
    const float* K  = (const float*)d_in[1];
    const float* V  = (const float*)d_in[2];
    const int*   VL = (const int*)d_in[3];
    const float* Wq = (const float*)d_in[4];
    const float* bq = (const float*)d_in[5];
    const float* Wk = (const float*)d_in[6];
    const float* bk = (const float*)d_in[7];
    const float* Wv = (const float*)d_in[8];
    const float* bv = (const float*)d_in[9];
    const float* Wo = (const float*)d_in[10];
    const float* bo = (const float*)d_in[11];

    char* ws = (char*)d_ws;
    _Float16* WT   = (_Float16*)ws;                                  // 2 MiB: 4 x 512x512 fp16
    _Float16* qws  = (_Float16*)(ws + (size_t)(2)  * 1024 * 1024);   // 8 MiB  [bh][s][hd]
    _Float16* kws  = (_Float16*)(ws + (size_t)(10) * 1024 * 1024);   // 8 MiB  [bh][s][hd]
    _Float16* aout = (_Float16*)(ws + (size_t)(18) * 1024 * 1024);   // 8 MiB  [8192,512]
    _Float16* vtws = (_Float16*)(ws + (size_t)(26) * 1024 * 1024);   // 8 MiB  [bh][hd][s] (direct from K2)

    transpose_w_kernel<<<dim3(8, 8, 4), 256, 0, stream>>>(Wq, Wk, Wv, Wo, WT);
    gemm_qkv_kernel<<<dim3(64, 4, 3), 256, 0, stream>>>(Q, K, V, WT, bq, bk, bv, qws, kws, vtws);
    attn_kernel<<<dim3(1024, 1, 1), 256, 0, stream>>>(qws, kws, vtws, VL, aout);
    gemm_out_kernel<<<dim3(64, 4, 1), 256, 0, stream>>>(aout, WT + (size_t)3 * 512 * 512, bo, (float*)d_out);
}

// Round 6
// 202.016 us; speedup vs baseline: 1.6280x; 1.0243x over previous
//
#include <hip/hip_runtime.h>
#include <hip/hip_bf16.h>

typedef _Float16 half8 __attribute__((ext_vector_type(8)));
typedef _Float16 half4 __attribute__((ext_vector_type(4)));
typedef float floatx4 __attribute__((ext_vector_type(4)));

#define LOG2E 1.44269504088896340736f

__device__ __forceinline__ half8 cvt8r(floatx4 a, floatx4 b) {
    half8 h;
    h[0] = (_Float16)a[0]; h[1] = (_Float16)a[1]; h[2] = (_Float16)a[2]; h[3] = (_Float16)a[3];
    h[4] = (_Float16)b[0]; h[5] = (_Float16)b[1]; h[6] = (_Float16)b[2]; h[7] = (_Float16)b[3];
    return h;
}

// ---------------- K1: transpose + convert W (f32 [512x512]) -> WT fp16 [n][k] ----------------
__global__ __launch_bounds__(256) void transpose_w_kernel(
        const float* __restrict__ Wq, const float* __restrict__ Wk,
        const float* __restrict__ Wv, const float* __restrict__ Wo,
        _Float16* __restrict__ out) {
    const float* W = (blockIdx.z == 0) ? Wq : (blockIdx.z == 1) ? Wk : (blockIdx.z == 2) ? Wv : Wo;
    _Float16* o = out + (size_t)blockIdx.z * 512 * 512;
    __shared__ __align__(16) _Float16 t[64][72];
    int r0 = blockIdx.x * 64, c0 = blockIdx.y * 64;
    int tid = threadIdx.x;
    for (int i = 0; i < 2; i++) {
        int f = i * 256 + tid;
        int row = f >> 3, seg = f & 7;
        const float* p = W + (size_t)(r0 + row) * 512 + c0 + seg * 8;
        *(half8*)&t[row][seg * 8] = cvt8r(*(const floatx4*)p, *(const floatx4*)(p + 4));
    }
    __syncthreads();
    for (int i = 0; i < 2; i++) {
        int f = i * 256 + tid;
        int crow = f >> 3, seg = f & 7;
        half8 hv;
        for (int j = 0; j < 8; j++) hv[j] = t[seg * 8 + j][crow];
        *(half8*)(o + (size_t)(c0 + crow) * 512 + r0 + seg * 8) = hv;
    }
}

// ---------------- K2: QKV projection GEMM (reg-prefetch dbuf); V written transposed ----------------
__global__ __launch_bounds__(256) void gemm_qkv_kernel(
        const float* __restrict__ Xq, const float* __restrict__ Xk, const float* __restrict__ Xv,
        const _Float16* __restrict__ WTall,
        const float* __restrict__ bq, const float* __restrict__ bk, const float* __restrict__ bv,
        _Float16* __restrict__ qo, _Float16* __restrict__ ko2, _Float16* __restrict__ vto) {
    int z = blockIdx.z;
    const float* X = (z == 0) ? Xq : (z == 1) ? Xk : Xv;
    const _Float16* BT = WTall + (size_t)z * 512 * 512;
    const float* bias = (z == 0) ? bq : (z == 1) ? bk : bv;

    __shared__ __align__(16) _Float16 Asm[128][72];
    __shared__ __align__(16) _Float16 Bsm[128][72];

    int tid = threadIdx.x;
    int wave = tid >> 6, lane = tid & 63;
    int lrow = lane & 15, quad = lane >> 4;
    int m0 = (wave >> 1) * 64, n0 = (wave & 1) * 64;
    int mBase = blockIdx.x * 128, nBase = blockIdx.y * 128;

    const floatx4 fz = {0.f, 0.f, 0.f, 0.f};
    floatx4 acc[4][4];
    for (int i = 0; i < 4; i++) for (int j = 0; j < 4; j++) acc[i][j] = fz;

    floatx4 areg[4][2];
    half8 breg[4];
    int srow[4], sseg[4];
    for (int i = 0; i < 4; i++) { int f = i * 256 + tid; srow[i] = f >> 3; sseg[i] = f & 7; }

    // prologue: load kb=0
    for (int i = 0; i < 4; i++) {
        const float* pa = X + (size_t)(mBase + srow[i]) * 512 + sseg[i] * 8;
        areg[i][0] = *(const floatx4*)pa;
        areg[i][1] = *(const floatx4*)(pa + 4);
        breg[i] = *(const half8*)(BT + (size_t)(nBase + srow[i]) * 512 + sseg[i] * 8);
    }

    for (int kb = 0; kb < 512; kb += 64) {
        for (int i = 0; i < 4; i++) {
            *(half8*)&Asm[srow[i]][sseg[i] * 8] = cvt8r(areg[i][0], areg[i][1]);
            *(half8*)&Bsm[srow[i]][sseg[i] * 8] = breg[i];
        }
        __syncthreads();
        if (kb + 64 < 512) {
            int kn = kb + 64;
            for (int i = 0; i < 4; i++) {
                const float* pa = X + (size_t)(mBase + srow[i]) * 512 + kn + sseg[i] * 8;
                areg[i][0] = *(const floatx4*)pa;
                areg[i][1] = *(const floatx4*)(pa + 4);
                breg[i] = *(const half8*)(BT + (size_t)(nBase + srow[i]) * 512 + kn + sseg[i] * 8);
            }
        }
        for (int kc = 0; kc < 2; kc++) {
            int ko_ = kc * 32 + quad * 8;
            half8 a[4], b[4];
            for (int mt = 0; mt < 4; mt++) a[mt] = *(const half8*)&Asm[m0 + mt * 16 + lrow][ko_];
            for (int nt = 0; nt < 4; nt++) b[nt] = *(const half8*)&Bsm[n0 + nt * 16 + lrow][ko_];
            for (int mt = 0; mt < 4; mt++)
                for (int nt = 0; nt < 4; nt++)
                    acc[mt][nt] = __builtin_amdgcn_mfma_f32_16x16x32_f16(a[mt], b[nt], acc[mt][nt], 0, 0, 0);
        }
        __syncthreads();
    }

    if (z == 2) {
        for (int nt = 0; nt < 4; nt++) {
            int gc = nBase + n0 + nt * 16 + lrow;
            float bb = bias[gc];
            int h = gc >> 6, hd = gc & 63;
            for (int mt = 0; mt < 4; mt++) {
                int gr = mBase + m0 + mt * 16 + quad * 4;
                int b_ = gr >> 11, s = gr & 2047;
                half4 hv;
                for (int r = 0; r < 4; r++) hv[r] = (_Float16)(acc[mt][nt][r] + bb);
                *(half4*)(vto + (((size_t)(b_ * 8 + h) * 64 + hd) * 2048 + s)) = hv;
            }
        }
    } else {
        _Float16* out = (z == 0) ? qo : ko2;
        for (int nt = 0; nt < 4; nt++) {
            int gc = nBase + n0 + nt * 16 + lrow;
            float bb = bias[gc];
            int h = gc >> 6, hd = gc & 63;
            for (int mt = 0; mt < 4; mt++) {
                for (int r = 0; r < 4; r++) {
                    int gr = mBase + m0 + mt * 16 + quad * 4 + r;
                    int b_ = gr >> 11, s = gr & 2047;
                    out[(((size_t)b_ * 8 + h) * 2048 + s) * 64 + hd] = (_Float16)(acc[mt][nt][r] + bb);
                }
            }
        }
    }
}

// ---------------- K3: flash attention v4: S^T trick + register-prefetch double buffer ----------------
__global__ __launch_bounds__(256) void attn_kernel(
        const _Float16* __restrict__ qws, const _Float16* __restrict__ kws, const _Float16* __restrict__ vtws,
        const int* __restrict__ vlens, _Float16* __restrict__ aout) {
    int idx = blockIdx.x;
    int b = ((idx & 3) + (idx >> 8)) & 3;
    int h = (idx >> 2) & 7;
    int q0 = ((idx >> 5) & 31) * 64;
    int bh = b * 8 + h;
    int L = vlens[b];
    bool uni = (L == 0);
    int nkt = uni ? 32 : ((L + 63) >> 6);
    int tid = threadIdx.x;
    int wave = tid >> 6, lane = tid & 63;
    int lrow = lane & 15, quad = lane >> 4;

    __shared__ __align__(16) _Float16 ksm[64][72];
    __shared__ __align__(16) _Float16 vtsm[80][72];  // 0..63: V^T tile; 64: ones; 65..79: zeros

    for (int i = tid; i < 15 * 36; i += 256) {
        int r = i / 36, c = i % 36;
        ((float*)&vtsm[65 + r][0])[c] = 0.0f;
    }
    if (tid < 64) vtsm[64][tid] = (_Float16)1.0f;

    const _Float16* qbase = qws + ((size_t)bh * 2048 + q0) * 64;
    const _Float16* kbase = kws + (size_t)bh * 2048 * 64;
    const _Float16* vtbase = vtws + (size_t)bh * 64 * 2048;

    half8 qf[2];
    for (int kc = 0; kc < 2; kc++) {
        qf[kc] = *(const half8*)(qbase + (wave * 16 + lrow) * 64 + kc * 32 + quad * 8);
        qf[kc] = qf[kc] * (_Float16)(0.125f * LOG2E);   // fold softmax scale into Q
    }

    const floatx4 fz = {0.f, 0.f, 0.f, 0.f};
    floatx4 oacc[5];
    for (int nt = 0; nt < 5; nt++) oacc[nt] = fz;

    // staging coords: thread covers chunks f0=tid, f1=256+tid
    int row0 = tid >> 3, seg = tid & 7;          // rows 0..31 / 32..63
    half8 kreg[2], vreg[2];
    {
        const _Float16* kt0 = kbase;
        const _Float16* vt0 = vtbase;
        kreg[0] = *(const half8*)(kt0 + tid * 8);
        kreg[1] = *(const half8*)(kt0 + (256 + tid) * 8);
        vreg[0] = *(const half8*)(vt0 + (size_t)row0 * 2048 + seg * 8);
        vreg[1] = *(const half8*)(vt0 + (size_t)(row0 + 32) * 2048 + seg * 8);
    }

    for (int kt = 0; kt < nkt; kt++) {
        *(half8*)&ksm[row0][seg * 8]        = kreg[0];
        *(half8*)&ksm[row0 + 32][seg * 8]   = kreg[1];
        *(half8*)&vtsm[row0][seg * 8]       = vreg[0];
        *(half8*)&vtsm[row0 + 32][seg * 8]  = vreg[1];
        __syncthreads();

        if (kt + 1 < nkt) {   // prefetch next tile into registers during compute
            const _Float16* ktn = kbase + (size_t)(kt + 1) * 64 * 64;
            const _Float16* vtn = vtbase + (kt + 1) * 64;
            kreg[0] = *(const half8*)(ktn + tid * 8);
            kreg[1] = *(const half8*)(ktn + (256 + tid) * 8);
            vreg[0] = *(const half8*)(vtn + (size_t)row0 * 2048 + seg * 8);
            vreg[1] = *(const half8*)(vtn + (size_t)(row0 + 32) * 2048 + seg * 8);
        }

        // S^T = K·Q^T : C-layout (key = km*16+quad*4+r, q = lrow)
        floatx4 sacc[4];
        for (int km = 0; km < 4; km++) sacc[km] = fz;
        for (int kc = 0; kc < 2; kc++) {
            int ko_ = kc * 32 + quad * 8;
            for (int km = 0; km < 4; km++) {
                half8 kf = *(const half8*)&ksm[km * 16 + lrow][ko_];
                sacc[km] = __builtin_amdgcn_mfma_f32_16x16x32_f16(kf, qf[kc], sacc[km], 0, 0, 0);
            }
        }

        half4 pf[4];
        int kb0 = kt * 64 + quad * 4;
        for (int km = 0; km < 4; km++) {
            int kb = kb0 + km * 16;
            for (int r = 0; r < 4; r++) {
                float p = uni ? 1.0f : ((kb + r < L) ? exp2f(sacc[km][r]) : 0.0f);
                pf[km][r] = (_Float16)p;
            }
        }

        for (int km = 0; km < 4; km++) {
            int kk = km * 16 + quad * 4;
            for (int nt = 0; nt < 5; nt++) {
                half4 bvf = *(const half4*)&vtsm[nt * 16 + lrow][kk];
                oacc[nt] = __builtin_amdgcn_mfma_f32_16x16x16f16(pf[km], bvf, oacc[nt], 0, 0, 0);
            }
        }
        __syncthreads();
    }

    float inv[4];
    for (int r = 0; r < 4; r++)
        inv[r] = 1.0f / __shfl(oacc[4][r], quad << 4, 64);

    for (int nt = 0; nt < 4; nt++) {
        for (int r = 0; r < 4; r++) {
            int s = q0 + wave * 16 + quad * 4 + r;
            aout[((size_t)b * 2048 + s) * 512 + h * 64 + nt * 16 + lrow] =
                (_Float16)(oacc[nt][r] * inv[r]);
        }
    }
}

// ---------------- K4: output projection (reg-prefetch dbuf): attn_out @ Wo + bo -> f32 ----------------
__global__ __launch_bounds__(256) void gemm_out_kernel(
        const _Float16* __restrict__ A, const _Float16* __restrict__ BT,
        const float* __restrict__ bias, float* __restrict__ out) {
    __shared__ __align__(16) _Float16 Asm[128][72];
    __shared__ __align__(16) _Float16 Bsm[128][72];

    int tid = threadIdx.x;
    int wave = tid >> 6, lane = tid & 63;
    int lrow = lane & 15, quad = lane >> 4;
    int m0 = (wave >> 1) * 64, n0 = (wave & 1) * 64;
    int mBase = blockIdx.x * 128, nBase = blockIdx.y * 128;

    const floatx4 fz = {0.f, 0.f, 0.f, 0.f};
    floatx4 acc[4][4];
    for (int i = 0; i < 4; i++) for (int j = 0; j < 4; j++) acc[i][j] = fz;

    half8 areg[4], breg[4];
    int srow[4], sseg[4];
    for (int i = 0; i < 4; i++) { int f = i * 256 + tid; srow[i] = f >> 3; sseg[i] = f & 7; }
    for (int i = 0; i < 4; i++) {
        areg[i] = *(const half8*)(A + (size_t)(mBase + srow[i]) * 512 + sseg[i] * 8);
        breg[i] = *(const half8*)(BT + (size_t)(nBase + srow[i]) * 512 + sseg[i] * 8);
    }

    for (int kb = 0; kb < 512; kb += 64) {
        for (int i = 0; i < 4; i++) {
            *(half8*)&Asm[srow[i]][sseg[i] * 8] = areg[i];
            *(half8*)&Bsm[srow[i]][sseg[i] * 8] = breg[i];
        }
        __syncthreads();
        if (kb + 64 < 512) {
            int kn = kb + 64;
            for (int i = 0; i < 4; i++) {
                areg[i] = *(const half8*)(A + (size_t)(mBase + srow[i]) * 512 + kn + sseg[i] * 8);
                breg[i] = *(const half8*)(BT + (size_t)(nBase + srow[i]) * 512 + kn + sseg[i] * 8);
            }
        }
        for (int kc = 0; kc < 2; kc++) {
            int ko_ = kc * 32 + quad * 8;
            half8 a[4], b[4];
            for (int mt = 0; mt < 4; mt++) a[mt] = *(const half8*)&Asm[m0 + mt * 16 + lrow][ko_];
            for (int nt = 0; nt < 4; nt++) b[nt] = *(const half8*)&Bsm[n0 + nt * 16 + lrow][ko_];
            for (int mt = 0; mt < 4; mt++)
                for (int nt = 0; nt < 4; nt++)
                    acc[mt][nt] = __builtin_amdgcn_mfma_f32_16x16x32_f16(a[mt], b[nt], acc[mt][nt], 0, 0, 0);
        }
        __syncthreads();
    }

    for (int nt = 0; nt < 4; nt++) {
        int gc = nBase + n0 + nt * 16 + lrow;
        float bb = bias[gc];
        for (int mt = 0; mt < 4; mt++) {
            for (int r = 0; r < 4; r++) {
                int gr = mBase + m0 + mt * 16 + quad * 4 + r;
                out[(size_t)gr * 512 + gc] = acc[mt][nt][r] + bb;
            }
        }
    }
}

extern "C" void kernel_launch(void* const* d_in, const int* in_sizes, int n_in,
                              void* d_out, int out_size, void* d_ws, size_t ws_size,
                              hipStream_t stream) {
    const float* Q  = (const float*)d_in[0];
    const float* K  = (const float*)d_in[1];
    const float* V  = (const float*)d_in[2];
    const int*   VL = (const int*)d_in[3];
    const float* Wq = (const float*)d_in[4];
    const float* bq = (const float*)d_in[5];
    const float* Wk = (const float*)d_in[6];
    const float* bk = (const float*)d_in[7];
    const float* Wv = (const float*)d_in[8];
    const float* bv = (const float*)d_in[9];
    const float* Wo = (const float*)d_in[10];
    const float* bo = (const float*)d_in[11];

    char* ws = (char*)d_ws;
    _Float16* WT   = (_Float16*)ws;                                  // 2 MiB
    _Float16* qws  = (_Float16*)(ws + (size_t)(2)  * 1024 * 1024);   // 8 MiB [bh][s][hd]
    _Float16* kws  = (_Float16*)(ws + (size_t)(10) * 1024 * 1024);   // 8 MiB [bh][s][hd]
    _Float16* aout = (_Float16*)(ws + (size_t)(18) * 1024 * 1024);   // 8 MiB [8192,512]
    _Float16* vtws = (_Float16*)(ws + (size_t)(26) * 1024 * 1024);   // 8 MiB [bh][hd][s]

    transpose_w_kernel<<<dim3(8, 8, 4), 256, 0, stream>>>(Wq, Wk, Wv, Wo, WT);
    gemm_qkv_kernel<<<dim3(64, 4, 3), 256, 0, stream>>>(Q, K, V, WT, bq, bk, bv, qws, kws, vtws);
    attn_kernel<<<dim3(1024, 1, 1), 256, 0, stream>>>(qws, kws, vtws, VL, aout);
    gemm_out_kernel<<<dim3(64, 4, 1), 256, 0, stream>>>(aout, WT + (size_t)3 * 512 * 512, bo, (float*)d_out);
}

// Round 8
// 194.084 us; speedup vs baseline: 1.6945x; 1.0409x over previous
//
#include <hip/hip_runtime.h>
#include <hip/hip_bf16.h>

typedef _Float16 half8 __attribute__((ext_vector_type(8)));
typedef _Float16 half4 __attribute__((ext_vector_type(4)));
typedef float floatx4 __attribute__((ext_vector_type(4)));

#define LOG2E 1.44269504088896340736f

__device__ __forceinline__ half8 cvt8r(floatx4 a, floatx4 b) {
    half8 h;
    h[0] = (_Float16)a[0]; h[1] = (_Float16)a[1]; h[2] = (_Float16)a[2]; h[3] = (_Float16)a[3];
    h[4] = (_Float16)b[0]; h[5] = (_Float16)b[1]; h[6] = (_Float16)b[2]; h[7] = (_Float16)b[3];
    return h;
}

// ---------------- K1: transpose + convert W (f32 [512x512]) -> WT fp16 [n][k] ----------------
__global__ __launch_bounds__(256) void transpose_w_kernel(
        const float* __restrict__ Wq, const float* __restrict__ Wk,
        const float* __restrict__ Wv, const float* __restrict__ Wo,
        _Float16* __restrict__ out) {
    const float* W = (blockIdx.z == 0) ? Wq : (blockIdx.z == 1) ? Wk : (blockIdx.z == 2) ? Wv : Wo;
    _Float16* o = out + (size_t)blockIdx.z * 512 * 512;
    __shared__ __align__(16) _Float16 t[64][72];
    int r0 = blockIdx.x * 64, c0 = blockIdx.y * 64;
    int tid = threadIdx.x;
    for (int i = 0; i < 2; i++) {
        int f = i * 256 + tid;
        int row = f >> 3, seg = f & 7;
        const float* p = W + (size_t)(r0 + row) * 512 + c0 + seg * 8;
        *(half8*)&t[row][seg * 8] = cvt8r(*(const floatx4*)p, *(const floatx4*)(p + 4));
    }
    __syncthreads();
    for (int i = 0; i < 2; i++) {
        int f = i * 256 + tid;
        int crow = f >> 3, seg = f & 7;
        half8 hv;
        for (int j = 0; j < 8; j++) hv[j] = t[seg * 8 + j][crow];
        *(half8*)(o + (size_t)(c0 + crow) * 512 + r0 + seg * 8) = hv;
    }
}

// ---------------- K2: QKV projection GEMM, 64x128 tiles (reg-prefetch dbuf); V transposed ----------------
__global__ __launch_bounds__(256) void gemm_qkv_kernel(
        const float* __restrict__ Xq, const float* __restrict__ Xk, const float* __restrict__ Xv,
        const _Float16* __restrict__ WTall,
        const float* __restrict__ bq, const float* __restrict__ bk, const float* __restrict__ bv,
        _Float16* __restrict__ qo, _Float16* __restrict__ ko2, _Float16* __restrict__ vto) {
    int z = blockIdx.z;
    const float* X = (z == 0) ? Xq : (z == 1) ? Xk : Xv;
    const _Float16* BT = WTall + (size_t)z * 512 * 512;
    const float* bias = (z == 0) ? bq : (z == 1) ? bk : bv;

    __shared__ __align__(16) _Float16 Asm[64][72];
    __shared__ __align__(16) _Float16 Bsm[128][72];

    int tid = threadIdx.x;
    int wave = tid >> 6, lane = tid & 63;
    int lrow = lane & 15, quad = lane >> 4;
    int mBase = blockIdx.x * 64, nBase = blockIdx.y * 128;
    int mrow = wave * 16 + lrow;   // this wave's 16 A-rows

    const floatx4 fz = {0.f, 0.f, 0.f, 0.f};
    floatx4 acc[8];
    for (int i = 0; i < 8; i++) acc[i] = fz;

    // staging coords: A = 2 chunks/thread (rows 0..63), B = 4 chunks/thread (rows 0..127)
    int arow[2], aseg[2], brow[4], bseg[4];
    for (int i = 0; i < 2; i++) { int f = i * 256 + tid; arow[i] = f >> 3; aseg[i] = f & 7; }
    for (int i = 0; i < 4; i++) { int f = i * 256 + tid; brow[i] = f >> 3; bseg[i] = f & 7; }

    floatx4 areg[2][2];
    half8 breg[4];
    for (int i = 0; i < 2; i++) {
        const float* pa = X + (size_t)(mBase + arow[i]) * 512 + aseg[i] * 8;
        areg[i][0] = *(const floatx4*)pa;
        areg[i][1] = *(const floatx4*)(pa + 4);
    }
    for (int i = 0; i < 4; i++)
        breg[i] = *(const half8*)(BT + (size_t)(nBase + brow[i]) * 512 + bseg[i] * 8);

    for (int kb = 0; kb < 512; kb += 64) {
        for (int i = 0; i < 2; i++) *(half8*)&Asm[arow[i]][aseg[i] * 8] = cvt8r(areg[i][0], areg[i][1]);
        for (int i = 0; i < 4; i++) *(half8*)&Bsm[brow[i]][bseg[i] * 8] = breg[i];
        __syncthreads();
        if (kb + 64 < 512) {
            int kn = kb + 64;
            for (int i = 0; i < 2; i++) {
                const float* pa = X + (size_t)(mBase + arow[i]) * 512 + kn + aseg[i] * 8;
                areg[i][0] = *(const floatx4*)pa;
                areg[i][1] = *(const floatx4*)(pa + 4);
            }
            for (int i = 0; i < 4; i++)
                breg[i] = *(const half8*)(BT + (size_t)(nBase + brow[i]) * 512 + kn + bseg[i] * 8);
        }
        for (int kc = 0; kc < 2; kc++) {
            int ko_ = kc * 32 + quad * 8;
            half8 a = *(const half8*)&Asm[mrow][ko_];
            for (int nt = 0; nt < 8; nt++) {
                half8 b = *(const half8*)&Bsm[nt * 16 + lrow][ko_];
                acc[nt] = __builtin_amdgcn_mfma_f32_16x16x32_f16(a, b, acc[nt], 0, 0, 0);
            }
        }
        __syncthreads();
    }

    if (z == 2) {
        for (int nt = 0; nt < 8; nt++) {
            int gc = nBase + nt * 16 + lrow;
            float bb = bias[gc];
            int h = gc >> 6, hd = gc & 63;
            int gr = mBase + wave * 16 + quad * 4;
            int b_ = gr >> 11, s = gr & 2047;
            half4 hv;
            for (int r = 0; r < 4; r++) hv[r] = (_Float16)(acc[nt][r] + bb);
            *(half4*)(vto + (((size_t)(b_ * 8 + h) * 64 + hd) * 2048 + s)) = hv;
        }
    } else {
        _Float16* out = (z == 0) ? qo : ko2;
        for (int nt = 0; nt < 8; nt++) {
            int gc = nBase + nt * 16 + lrow;
            float bb = bias[gc];
            int h = gc >> 6, hd = gc & 63;
            for (int r = 0; r < 4; r++) {
                int gr = mBase + wave * 16 + quad * 4 + r;
                int b_ = gr >> 11, s = gr & 2047;
                out[(((size_t)b_ * 8 + h) * 2048 + s) * 64 + hd] = (_Float16)(acc[nt][r] + bb);
            }
        }
    }
}

// ---------------- K3: flash attention v5: 2 waves x 32 q-rows, S^T trick, reg P ----------------
__global__ __launch_bounds__(128) void attn_kernel(
        const _Float16* __restrict__ qws, const _Float16* __restrict__ kws, const _Float16* __restrict__ vtws,
        const int* __restrict__ vlens, _Float16* __restrict__ aout) {
    int idx = blockIdx.x;
    int b = ((idx & 3) + (idx >> 8)) & 3;
    int h = (idx >> 2) & 7;
    int q0 = ((idx >> 5) & 31) * 64;
    int bh = b * 8 + h;
    int L = vlens[b];
    bool uni = (L == 0);
    int nkt = uni ? 32 : ((L + 63) >> 6);
    int nfull = uni ? 0 : (L >> 6);           // tiles [0, nfull) are fully valid
    int tid = threadIdx.x;
    int w = tid >> 6, lane = tid & 63;
    int lrow = lane & 15, quad = lane >> 4;

    __shared__ __align__(16) _Float16 ksm[64][72];
    __shared__ __align__(16) _Float16 vtsm[80][72];   // 0..63: V^T tile; 64: ones; 65..79: zeros

    for (int i = tid; i < 15 * 36; i += 128) {
        int r = i / 36, c = i % 36;
        ((float*)&vtsm[65 + r][0])[c] = 0.0f;
    }
    if (tid < 64) vtsm[64][tid] = (_Float16)1.0f;

    const _Float16* qbase = qws + ((size_t)bh * 2048 + q0) * 64;
    const _Float16* kbase = kws + (size_t)bh * 2048 * 64;
    const _Float16* vtbase = vtws + (size_t)bh * 64 * 2048;

    half8 qf[2][2];    // [qt][kc], scale folded in
    for (int qt = 0; qt < 2; qt++)
        for (int kc = 0; kc < 2; kc++) {
            qf[qt][kc] = *(const half8*)(qbase + (w * 32 + qt * 16 + lrow) * 64 + kc * 32 + quad * 8);
            qf[qt][kc] = qf[qt][kc] * (_Float16)(0.125f * LOG2E);
        }

    const floatx4 fz = {0.f, 0.f, 0.f, 0.f};
    floatx4 oacc[2][5];
    for (int qt = 0; qt < 2; qt++) for (int nt = 0; nt < 5; nt++) oacc[qt][nt] = fz;

    // staging: 4 chunks each (128 threads x 8 halves x 4 = 4096 halves = 64x64 tile)
    int srow[4], sseg[4];
    for (int i = 0; i < 4; i++) { int f = i * 128 + tid; srow[i] = f >> 3; sseg[i] = f & 7; }
    half8 kreg[4], vreg[4];
    for (int i = 0; i < 4; i++) {
        kreg[i] = *(const half8*)(kbase + (i * 128 + tid) * 8);
        vreg[i] = *(const half8*)(vtbase + (size_t)srow[i] * 2048 + sseg[i] * 8);
    }

    for (int kt = 0; kt < nkt; kt++) {
        for (int i = 0; i < 4; i++) {
            *(half8*)&ksm[srow[i]][sseg[i] * 8]  = kreg[i];
            *(half8*)&vtsm[srow[i]][sseg[i] * 8] = vreg[i];
        }
        __syncthreads();
        if (kt + 1 < nkt) {
            const _Float16* ktn = kbase + (size_t)(kt + 1) * 64 * 64;
            const _Float16* vtn = vtbase + (kt + 1) * 64;
            for (int i = 0; i < 4; i++) {
                kreg[i] = *(const half8*)(ktn + (i * 128 + tid) * 8);
                vreg[i] = *(const half8*)(vtn + (size_t)srow[i] * 2048 + sseg[i] * 8);
            }
        }

        // S^T = K·(Q·c)^T : C-layout (key = km*16+quad*4+r, q = lrow)
        floatx4 sacc[2][4];
        for (int qt = 0; qt < 2; qt++) for (int km = 0; km < 4; km++) sacc[qt][km] = fz;
        for (int kc = 0; kc < 2; kc++) {
            int ko_ = kc * 32 + quad * 8;
            for (int km = 0; km < 4; km++) {
                half8 kf = *(const half8*)&ksm[km * 16 + lrow][ko_];
                sacc[0][km] = __builtin_amdgcn_mfma_f32_16x16x32_f16(kf, qf[0][kc], sacc[0][km], 0, 0, 0);
                sacc[1][km] = __builtin_amdgcn_mfma_f32_16x16x32_f16(kf, qf[1][kc], sacc[1][km], 0, 0, 0);
            }
        }

        half4 pf[2][4];
        if (kt < nfull) {
            // interior tile: no masking, no compares
            for (int qt = 0; qt < 2; qt++)
                for (int km = 0; km < 4; km++)
                    for (int r = 0; r < 4; r++)
                        pf[qt][km][r] = (_Float16)exp2f(sacc[qt][km][r]);
        } else {
            int kb0 = kt * 64 + quad * 4;
            for (int km = 0; km < 4; km++) {
                int kb = kb0 + km * 16;
                for (int qt = 0; qt < 2; qt++)
                    for (int r = 0; r < 4; r++) {
                        float p = uni ? 1.0f : ((kb + r < L) ? exp2f(sacc[qt][km][r]) : 0.0f);
                        pf[qt][km][r] = (_Float16)p;
                    }
            }
        }

        // PV (+ ones column for row sums); bvf shared across qt
        for (int km = 0; km < 4; km++) {
            int kk = km * 16 + quad * 4;
            for (int nt = 0; nt < 5; nt++) {
                half4 bvf = *(const half4*)&vtsm[nt * 16 + lrow][kk];
                oacc[0][nt] = __builtin_amdgcn_mfma_f32_16x16x16f16(pf[0][km], bvf, oacc[0][nt], 0, 0, 0);
                oacc[1][nt] = __builtin_amdgcn_mfma_f32_16x16x16f16(pf[1][km], bvf, oacc[1][nt], 0, 0, 0);
            }
        }
        __syncthreads();
    }

    for (int qt = 0; qt < 2; qt++) {
        float inv[4];
        for (int r = 0; r < 4; r++)
            inv[r] = 1.0f / __shfl(oacc[qt][4][r], quad << 4, 64);
        for (int nt = 0; nt < 4; nt++) {
            for (int r = 0; r < 4; r++) {
                int s = q0 + w * 32 + qt * 16 + quad * 4 + r;
                aout[((size_t)b * 2048 + s) * 512 + h * 64 + nt * 16 + lrow] =
                    (_Float16)(oacc[qt][nt][r] * inv[r]);
            }
        }
    }
}

// ---------------- K4: output projection, 64x128 tiles (reg-prefetch dbuf) -> f32 ----------------
__global__ __launch_bounds__(256) void gemm_out_kernel(
        const _Float16* __restrict__ A, const _Float16* __restrict__ BT,
        const float* __restrict__ bias, float* __restrict__ out) {
    __shared__ __align__(16) _Float16 Asm[64][72];
    __shared__ __align__(16) _Float16 Bsm[128][72];

    int tid = threadIdx.x;
    int wave = tid >> 6, lane = tid & 63;
    int lrow = lane & 15, quad = lane >> 4;
    int mBase = blockIdx.x * 64, nBase = blockIdx.y * 128;
    int mrow = wave * 16 + lrow;

    const floatx4 fz = {0.f, 0.f, 0.f, 0.f};
    floatx4 acc[8];
    for (int i = 0; i < 8; i++) acc[i] = fz;

    int arow[2], aseg[2], brow[4], bseg[4];
    for (int i = 0; i < 2; i++) { int f = i * 256 + tid; arow[i] = f >> 3; aseg[i] = f & 7; }
    for (int i = 0; i < 4; i++) { int f = i * 256 + tid; brow[i] = f >> 3; bseg[i] = f & 7; }

    half8 areg[2], breg[4];
    for (int i = 0; i < 2; i++)
        areg[i] = *(const half8*)(A + (size_t)(mBase + arow[i]) * 512 + aseg[i] * 8);
    for (int i = 0; i < 4; i++)
        breg[i] = *(const half8*)(BT + (size_t)(nBase + brow[i]) * 512 + bseg[i] * 8);

    for (int kb = 0; kb < 512; kb += 64) {
        for (int i = 0; i < 2; i++) *(half8*)&Asm[arow[i]][aseg[i] * 8] = areg[i];
        for (int i = 0; i < 4; i++) *(half8*)&Bsm[brow[i]][bseg[i] * 8] = breg[i];
        __syncthreads();
        if (kb + 64 < 512) {
            int kn = kb + 64;
            for (int i = 0; i < 2; i++)
                areg[i] = *(const half8*)(A + (size_t)(mBase + arow[i]) * 512 + kn + aseg[i] * 8);
            for (int i = 0; i < 4; i++)
                breg[i] = *(const half8*)(BT + (size_t)(nBase + brow[i]) * 512 + kn + bseg[i] * 8);
        }
        for (int kc = 0; kc < 2; kc++) {
            int ko_ = kc * 32 + quad * 8;
            half8 a = *(const half8*)&Asm[mrow][ko_];
            for (int nt = 0; nt < 8; nt++) {
                half8 b = *(const half8*)&Bsm[nt * 16 + lrow][ko_];
                acc[nt] = __builtin_amdgcn_mfma_f32_16x16x32_f16(a, b, acc[nt], 0, 0, 0);
            }
        }
        __syncthreads();
    }

    for (int nt = 0; nt < 8; nt++) {
        int gc = nBase + nt * 16 + lrow;
        float bb = bias[gc];
        for (int r = 0; r < 4; r++) {
            int gr = mBase + wave * 16 + quad * 4 + r;
            out[(size_t)gr * 512 + gc] = acc[nt][r] + bb;
        }
    }
}

extern "C" void kernel_launch(void* const* d_in, const int* in_sizes, int n_in,
                              void* d_out, int out_size, void* d_ws, size_t ws_size,
                              hipStream_t stream) {
    const float* Q  = (const float*)d_in[0];
    const float* K  = (const float*)d_in[1];
    const float* V  = (const float*)d_in[2];
    const int*   VL = (const int*)d_in[3];
    const float* Wq = (const float*)d_in[4];
    const float* bq = (const float*)d_in[5];
    const float* Wk = (const float*)d_in[6];
    const float* bk = (const float*)d_in[7];
    const float* Wv = (const float*)d_in[8];
    const float* bv = (const float*)d_in[9];
    const float* Wo = (const float*)d_in[10];
    const float* bo = (const float*)d_in[11];

    char* ws = (char*)d_ws;
    _Float16* WT   = (_Float16*)ws;                                  // 2 MiB
    _Float16* qws  = (_Float16*)(ws + (size_t)(2)  * 1024 * 1024);   // 8 MiB [bh][s][hd]
    _Float16* kws  = (_Float16*)(ws + (size_t)(10) * 1024 * 1024);   // 8 MiB [bh][s][hd]
    _Float16* aout = (_Float16*)(ws + (size_t)(18) * 1024 * 1024);   // 8 MiB [8192,512]
    _Float16* vtws = (_Float16*)(ws + (size_t)(26) * 1024 * 1024);   // 8 MiB [bh][hd][s]

    transpose_w_kernel<<<dim3(8, 8, 4), 256, 0, stream>>>(Wq, Wk, Wv, Wo, WT);
    gemm_qkv_kernel<<<dim3(128, 4, 3), 256, 0, stream>>>(Q, K, V, WT, bq, bk, bv, qws, kws, vtws);
    attn_kernel<<<dim3(1024, 1, 1), 128, 0, stream>>>(qws, kws, vtws, VL, aout);
    gemm_out_kernel<<<dim3(128, 4, 1), 256, 0, stream>>>(aout, WT + (size_t)3 * 512 * 512, bo, (float*)d_out);
}